// Round 8
// baseline (148.640 us; speedup 1.0000x reference)
//
#include <hip/hip_runtime.h>
#include <math.h>

// ---------------------------------------------------------------------------
// SelectiveAttention, bf16-MFMA, 3-kernel pipeline:
//   prep_weights:   Wi->WiT bf16, Wo->WoT bf16 (transposed for B-frags)
//   proj_in(value): kv = value @ Wi + bi -> kvp (row-major) + kvT (16-blocked)
//   band_attn_out:  q-proj (own strip, fused) -> banded QK^T -> mask -> PV
//                   -> @Wo + bo -> out
// B=4, S=4096, D=512, Dk=64, band=128.
//
// R8 (traffic-efficiency only; volume is already minimal):
//  - nontemporal loads for the streaming fp32 query/value reads and NT stores
//    for out: no reuse there, keeps L2 for the x17-reused kv intermediates.
//  - kvT re-blocked as [b][s/16][d][16]: proj_in writes one contiguous 2KB
//    tile per block (was 64 scattered 32B chunks at 8KB stride); band PV
//    reads become paired 32B segments.
//  - XCD swizzle on band strips (gs=(blk&7)*128+blk>>3): each XCD's strips
//    contiguous -> kv window ~600KB per XCD L2 instead of all 8MB.
// Timed loop still carries ~95-100us harness fill/restore (top-5 = fills).
//
// MFMA 16x16x32 bf16 layouts (m89-verified):
//   A-frag: lane l holds A[m=l&15][k=(l>>4)*8+j]  (16B contiguous)
//   B-frag: lane l holds B[k=(l>>4)*8+j][n=l&15]  (B^T storage -> 16B reads)
//   C/D:    lane l, reg r -> C[row=(l>>4)*4+r][col=l&15]
// ---------------------------------------------------------------------------

typedef __bf16 bf16;
using bf16x4  = __attribute__((ext_vector_type(4))) __bf16;
using bf16x8  = __attribute__((ext_vector_type(8))) __bf16;
using floatx4 = __attribute__((ext_vector_type(4))) float;

#define MFMA(a, b, c) __builtin_amdgcn_mfma_f32_16x16x32_bf16(a, b, c, 0, 0, 0)

__device__ __forceinline__ floatx4 nt_load4(const float* p) {
    return __builtin_nontemporal_load((const floatx4*)p);
}

// WiT[n][k]=Wi[k][n] (64x512 bf16), WoT[n][k]=Wo[k][n] (512x64 bf16).
__global__ __launch_bounds__(256) void prep_weights(
    const float* __restrict__ Wi, const float* __restrict__ Wo,
    bf16* __restrict__ WiT, bf16* __restrict__ WoT)
{
    __shared__ float T[64][65];
    const int blk = blockIdx.x, tid = threadIdx.x;
    if (blk < 8) {
        const int k0 = blk * 64;
        #pragma unroll
        for (int i = 0; i < 4; i++) {
            int idx4 = tid * 4 + i;
            int r = idx4 >> 4, c4 = (idx4 & 15) * 4;
            float4 f = *(const float4*)(Wi + (size_t)(k0 + r) * 64 + c4);
            T[r][c4 + 0] = f.x; T[r][c4 + 1] = f.y;
            T[r][c4 + 2] = f.z; T[r][c4 + 3] = f.w;
        }
        __syncthreads();
        #pragma unroll
        for (int i = 0; i < 2; i++) {
            int seg = tid * 2 + i;
            int n = seg >> 3, k8 = (seg & 7) * 8;
            bf16x8 v;
            #pragma unroll
            for (int j = 0; j < 8; j++) v[j] = (bf16)T[k8 + j][n];
            *(bf16x8*)(WiT + (size_t)n * 512 + k0 + k8) = v;
        }
    } else {
        const int n0 = (blk - 8) * 64;
        #pragma unroll
        for (int i = 0; i < 4; i++) {
            int idx4 = tid * 4 + i;
            int r = idx4 >> 4, c4 = (idx4 & 15) * 4;
            float4 f = *(const float4*)(Wo + (size_t)r * 512 + n0 + c4);
            T[r][c4 + 0] = f.x; T[r][c4 + 1] = f.y;
            T[r][c4 + 2] = f.z; T[r][c4 + 3] = f.w;
        }
        __syncthreads();
        #pragma unroll
        for (int i = 0; i < 2; i++) {
            int seg = tid * 2 + i;
            int n = seg >> 3, k8 = (seg & 7) * 8;
            bf16x8 v;
            #pragma unroll
            for (int j = 0; j < 8; j++) v[j] = (bf16)T[k8 + j][n];
            *(bf16x8*)(WoT + (size_t)(n0 + n) * 64 + k8) = v;
        }
    }
}

// One block = 16 rows of value. Wave w covers k in [w*128,(w+1)*128). LDS
// reduce -> kvp row-major + kvT blocked [b][s/16][d][16].
__global__ __launch_bounds__(256, 4) void proj_in_kernel(
    const float* __restrict__ v, const bf16* __restrict__ WiT,
    const float* __restrict__ bi, bf16* __restrict__ kvp,
    bf16* __restrict__ kvT, int K, int S)
{
    __shared__ float P[4][16][68];                    // [wave][row][col]
    const int tid = threadIdx.x;
    const int wave = tid >> 6, lane = tid & 63;
    const int lr = lane & 15, lq = lane >> 4;
    const int row0 = blockIdx.x * 16;
    const float* xrow = v + (size_t)(row0 + lr) * K + wave * 128;
    const bf16* wrow = WiT + wave * 128;

    floatx4 acc[4] = {};
    #pragma unroll
    for (int ks = 0; ks < 4; ks++) {
        const int k0 = ks * 32 + lq * 8;
        floatx4 a0 = nt_load4(xrow + k0);
        floatx4 a1 = nt_load4(xrow + k0 + 4);
        bf16x8 af;
        af[0] = (bf16)a0[0]; af[1] = (bf16)a0[1]; af[2] = (bf16)a0[2]; af[3] = (bf16)a0[3];
        af[4] = (bf16)a1[0]; af[5] = (bf16)a1[1]; af[6] = (bf16)a1[2]; af[7] = (bf16)a1[3];
        #pragma unroll
        for (int t = 0; t < 4; t++) {
            bf16x8 bfv = *(const bf16x8*)(wrow + (size_t)(t * 16 + lr) * K + k0);
            acc[t] = MFMA(af, bfv, acc[t]);
        }
    }
    #pragma unroll
    for (int t = 0; t < 4; t++)
        #pragma unroll
        for (int r = 0; r < 4; r++)
            P[wave][lq * 4 + r][t * 16 + lr] = acc[t][r];
    __syncthreads();

    {   // reduce + row-major write
        const int row = tid >> 4, c4 = (tid & 15) * 4;
        float4 s0 = *(const float4*)&P[0][row][c4];
        float4 s1 = *(const float4*)&P[1][row][c4];
        float4 s2 = *(const float4*)&P[2][row][c4];
        float4 s3 = *(const float4*)&P[3][row][c4];
        float4 bb = *(const float4*)(bi + c4);
        bf16x4 o;
        o[0] = (bf16)(s0.x + s1.x + s2.x + s3.x + bb.x);
        o[1] = (bf16)(s0.y + s1.y + s2.y + s3.y + bb.y);
        o[2] = (bf16)(s0.z + s1.z + s2.z + s3.z + bb.z);
        o[3] = (bf16)(s0.w + s1.w + s2.w + s3.w + bb.w);
        *(bf16x4*)(kvp + (size_t)(row0 + row) * 64 + c4) = o;
    }
    {   // kvT blocked write: [b][s/16][d][16]; block tile is contiguous 2KB
        const int d = tid >> 2, s4 = (tid & 3) * 4;
        const int b = row0 >> 12, s0r = row0 & (S - 1);
        const float bb = bi[d];
        bf16x4 o;
        #pragma unroll
        for (int i = 0; i < 4; i++) {
            float s = P[0][s4 + i][d] + P[1][s4 + i][d]
                    + P[2][s4 + i][d] + P[3][s4 + i][d] + bb;
            o[i] = (bf16)s;
        }
        *(bf16x4*)(kvT + (((size_t)b * (S >> 4) + (s0r >> 4)) * 64 + d) * 16 + s4) = o;
    }
}

// One block = one 16-query strip; 4 waves cooperate.
// Phase 0: fused q-proj of own strip (K-split x4, LDS reduce, +bi, *scale).
// Phase 1 (barrier-free per wave): 10 half-chunks (32 keys) split {3,3,2,2}:
//   QK^T -> mask -> private 32-wide S-strip -> PV partial acc.
// Phase 2: reduce acc via LDS -> shared bf16 att strip.
// Phase 3: each wave does 8 of 32 n-tiles of att @ Wo + bo.
__global__ __launch_bounds__(256, 4) void band_attn_out_kernel(
    const float* __restrict__ query, const bf16* __restrict__ WiT,
    const float* __restrict__ bi, const bf16* __restrict__ kvp,
    const bf16* __restrict__ kvT, const int* __restrict__ band_ptr,
    const bf16* __restrict__ WoT, const float* __restrict__ bo,
    float* __restrict__ out, int K, int S, float scale)
{
    __shared__ float P[4][16][68];                    // partials (q-proj, acc)
    __shared__ bf16 Ss[4][16][40];                    // per-wave 32-key S strip
    __shared__ bf16 St[16][88];                       // q strip / att strip
    const int tid = threadIdx.x;
    const int wave = tid >> 6, lane = tid & 63;
    const int lr = lane & 15, lq = lane >> 4;
    // XCD swizzle: blocks == x (mod 8) land on XCD x -> give each XCD a
    // contiguous run of 128 strips so its kv window fits hot in its L2.
    const int blk = blockIdx.x;
    const int gs = (blk & 7) * 128 + (blk >> 3);      // strip id
    const int b = gs >> 8;                            // 256 strips per batch
    const int q0 = (gs & 255) * 16;
    const int band = band_ptr[0];

    // ---- phase 0: q-proj of rows [b*S+q0, +16) ----
    {
        const float* xrow = query + ((size_t)b * S + q0 + lr) * K + wave * 128;
        const bf16* wrow = WiT + wave * 128;
        floatx4 qa[4] = {};
        #pragma unroll
        for (int ks = 0; ks < 4; ks++) {
            const int k0 = ks * 32 + lq * 8;
            floatx4 a0 = nt_load4(xrow + k0);
            floatx4 a1 = nt_load4(xrow + k0 + 4);
            bf16x8 af;
            af[0] = (bf16)a0[0]; af[1] = (bf16)a0[1]; af[2] = (bf16)a0[2]; af[3] = (bf16)a0[3];
            af[4] = (bf16)a1[0]; af[5] = (bf16)a1[1]; af[6] = (bf16)a1[2]; af[7] = (bf16)a1[3];
            #pragma unroll
            for (int t = 0; t < 4; t++) {
                bf16x8 bfv = *(const bf16x8*)(wrow + (size_t)(t * 16 + lr) * K + k0);
                qa[t] = MFMA(af, bfv, qa[t]);
            }
        }
        #pragma unroll
        for (int t = 0; t < 4; t++)
            #pragma unroll
            for (int r = 0; r < 4; r++)
                P[wave][lq * 4 + r][t * 16 + lr] = qa[t][r];
    }
    __syncthreads();
    {   // reduce + bias + scale -> bf16 q strip
        const int row = tid >> 4, c4 = (tid & 15) * 4;
        float4 s0 = *(const float4*)&P[0][row][c4];
        float4 s1 = *(const float4*)&P[1][row][c4];
        float4 s2 = *(const float4*)&P[2][row][c4];
        float4 s3 = *(const float4*)&P[3][row][c4];
        float4 bb = *(const float4*)(bi + c4);
        bf16x4 o;
        o[0] = (bf16)((s0.x + s1.x + s2.x + s3.x + bb.x) * scale);
        o[1] = (bf16)((s0.y + s1.y + s2.y + s3.y + bb.y) * scale);
        o[2] = (bf16)((s0.z + s1.z + s2.z + s3.z + bb.z) * scale);
        o[3] = (bf16)((s0.w + s1.w + s2.w + s3.w + bb.w) * scale);
        *(bf16x4*)(&St[row][c4]) = o;
    }
    __syncthreads();
    bf16x8 qf0 = *(const bf16x8*)(&St[lr][lq * 8]);
    bf16x8 qf1 = *(const bf16x8*)(&St[lr][32 + lq * 8]);

    // ---- phase 1: 10 half-chunks of 32 keys; wave w does {w, w+4, w+8} ----
    floatx4 acc[4] = {};
    const int base = ((q0 - band) >> 6) * 64;         // floor-div chunk base
    const bf16* kvTb = kvT + (size_t)b * (S >> 4) * 1024;
    #pragma unroll
    for (int i = 0; i < 3; i++) {
        const int h = wave + i * 4;
        if (h < 10) {
            const int kj0 = base + h * 32;
            // QK^T for the 2 key 16-tiles of this half-chunk
            floatx4 sc[2] = {};
            #pragma unroll
            for (int t2 = 0; t2 < 2; t2++) {
                int kr = kj0 + t2 * 16 + lr;
                int krc = min(max(kr, 0), S - 1);     // clamp; masked below
                const bf16* kp = kvp + ((size_t)b * S + krc) * 64;
                bf16x8 b0 = *(const bf16x8*)(kp + lq * 8);
                bf16x8 b1 = *(const bf16x8*)(kp + 32 + lq * 8);
                sc[t2] = MFMA(qf0, b0, sc[t2]);
                sc[t2] = MFMA(qf1, b1, sc[t2]);
            }
            #pragma unroll
            for (int t2 = 0; t2 < 2; t2++) {
                int kj = kj0 + t2 * 16 + lr;
                bool kv_ok = (kj >= 0) && (kj < S);
                #pragma unroll
                for (int r = 0; r < 4; r++) {
                    int qi = q0 + lq * 4 + r;
                    int dlt = qi - kj; dlt = dlt < 0 ? -dlt : dlt;
                    float vv = (kv_ok && dlt <= band) ? sc[t2][r] : 0.f;
                    Ss[wave][lq * 4 + r][t2 * 16 + lr] = (bf16)vv;
                }
            }
            // same-wave LDS write->read: in-order per wave, no barrier needed
            bf16x8 sa = *(const bf16x8*)(&Ss[wave][lr][lq * 8]);
            int kb = kj0 + lq * 8;                    // 8-aligned segment
            int kbc = min(max(kb, 0), S - 8);         // clamp; S entries are 0
            const bf16* kchunk = kvTb + ((size_t)(kbc >> 4) * 64) * 16 + (kbc & 15);
            #pragma unroll
            for (int t = 0; t < 4; t++) {
                bf16x8 vb = *(const bf16x8*)(kchunk + (size_t)(t * 16 + lr) * 16);
                acc[t] = MFMA(sa, vb, acc[t]);
            }
        }
    }
    #pragma unroll
    for (int t = 0; t < 4; t++)
        #pragma unroll
        for (int r = 0; r < 4; r++)
            P[wave][lq * 4 + r][t * 16 + lr] = acc[t][r];
    __syncthreads();

    // ---- phase 2: reduce 4 partials -> bf16 att strip ----
    {
        const int row = tid >> 4, c4 = (tid & 15) * 4;
        float4 s0 = *(const float4*)&P[0][row][c4];
        float4 s1 = *(const float4*)&P[1][row][c4];
        float4 s2 = *(const float4*)&P[2][row][c4];
        float4 s3 = *(const float4*)&P[3][row][c4];
        bf16x4 o;
        o[0] = (bf16)(s0.x + s1.x + s2.x + s3.x);
        o[1] = (bf16)(s0.y + s1.y + s2.y + s3.y);
        o[2] = (bf16)(s0.z + s1.z + s2.z + s3.z);
        o[3] = (bf16)(s0.w + s1.w + s2.w + s3.w);
        *(bf16x4*)(&St[row][c4]) = o;
    }
    __syncthreads();

    // ---- phase 3: epilogue quarter per wave: n-tiles wave*8 .. wave*8+7 ----
    bf16x8 af0 = *(const bf16x8*)(&St[lr][lq * 8]);
    bf16x8 af1 = *(const bf16x8*)(&St[lr][32 + lq * 8]);
    float* orow = out + ((size_t)b * S + q0) * 512;
    #pragma unroll
    for (int i = 0; i < 8; i++) {
        const int tp = wave * 8 + i;
        const bf16* wp = WoT + (size_t)(tp * 16 + lr) * 64;
        bf16x8 b0 = *(const bf16x8*)(wp + lq * 8);
        bf16x8 b1 = *(const bf16x8*)(wp + 32 + lq * 8);
        floatx4 o = {};
        o = MFMA(af0, b0, o);
        o = MFMA(af1, b1, o);
        float bb = bo[tp * 16 + lr];
        #pragma unroll
        for (int r = 0; r < 4; r++)
            __builtin_nontemporal_store(o[r] + bb,
                &orow[(size_t)(lq * 4 + r) * 512 + tp * 16 + lr]);
    }
}

extern "C" void kernel_launch(void* const* d_in, const int* in_sizes, int n_in,
                              void* d_out, int out_size, void* d_ws, size_t ws_size,
                              hipStream_t stream) {
    const float* query = (const float*)d_in[0];
    const float* value = (const float*)d_in[1];
    const float* Wi    = (const float*)d_in[2];
    const float* bi    = (const float*)d_in[3];
    const float* Wo    = (const float*)d_in[4];
    const float* bo    = (const float*)d_in[5];
    const int*   band  = (const int*)d_in[6];
    float* out = (float*)d_out;

    const int Dk = in_sizes[3];            // 64
    const int D  = in_sizes[5];            // 512
    const int S  = 4096;                   // fixed by the benchmark
    const int BS = in_sizes[0] / D;        // 16384
    const int B  = BS / S;                 // 4
    const float scale = 1.0f / sqrtf((float)Dk);

    bf16* WiT = (bf16*)d_ws;
    bf16* WoT = WiT + 32768;
    bf16* kvp = WoT + 32768;
    bf16* kvT = kvp + (size_t)BS * 64;

    prep_weights<<<16, 256, 0, stream>>>(Wi, Wo, WiT, WoT);

    proj_in_kernel<<<dim3(BS / 16), 256, 0, stream>>>(
        value, WiT, bi, kvp, kvT, D, S);

    band_attn_out_kernel<<<dim3(BS / 16), 256, 0, stream>>>(
        query, WiT, bi, kvp, kvT, band, WoT, bo, out, D, S, scale);
}

// Round 9
// 143.928 us; speedup vs baseline: 1.0327x; 1.0327x over previous
//
#include <hip/hip_runtime.h>
#include <math.h>

// ---------------------------------------------------------------------------
// SelectiveAttention, bf16-MFMA, 3-kernel pipeline (R9 = exact revert to R7,
// the best measured configuration at 144.4 us):
//   prep_weights:   Wi->WiT bf16, Wo->WoT bf16 (transposed for B-frags)
//   proj_in(value): kv = value @ Wi + bi -> kvp (row-major) + kvT (transposed)
//   band_attn_out:  q-proj (own strip, fused) -> banded QK^T -> mask -> PV
//                   -> @Wo + bo -> out
// B=4, S=4096, D=512, Dk=64, band=128.
//
// R8's bundle (NT loads/stores, kvT re-block, XCD swizzle) regressed to 148.6:
// NT stores defeat L2 write-combining on 64B-granule out writes, and the XCD
// swizzle destroyed adjacent-strip kv sharing in L2. Reverted wholesale.
//
// Accounting at 144.4 us: ~100 us harness fill/restore (fixed; top-5
// dispatches are fillBufferAligned) + ~44 us kernels vs ~31 us floor
// (161 MB mandatory traffic @6.3 TB/s + prep + 3 launches).
//
// MFMA 16x16x32 bf16 layouts (m89-verified):
//   A-frag: lane l holds A[m=l&15][k=(l>>4)*8+j]  (16B contiguous)
//   B-frag: lane l holds B[k=(l>>4)*8+j][n=l&15]  (B^T storage -> 16B reads)
//   C/D:    lane l, reg r -> C[row=(l>>4)*4+r][col=l&15]
// ---------------------------------------------------------------------------

typedef __bf16 bf16;
using bf16x4  = __attribute__((ext_vector_type(4))) __bf16;
using bf16x8  = __attribute__((ext_vector_type(8))) __bf16;
using floatx4 = __attribute__((ext_vector_type(4))) float;

#define MFMA(a, b, c) __builtin_amdgcn_mfma_f32_16x16x32_bf16(a, b, c, 0, 0, 0)

// WiT[n][k]=Wi[k][n] (64x512 bf16), WoT[n][k]=Wo[k][n] (512x64 bf16).
__global__ __launch_bounds__(256) void prep_weights(
    const float* __restrict__ Wi, const float* __restrict__ Wo,
    bf16* __restrict__ WiT, bf16* __restrict__ WoT)
{
    __shared__ float T[64][65];
    const int blk = blockIdx.x, tid = threadIdx.x;
    if (blk < 8) {
        const int k0 = blk * 64;
        #pragma unroll
        for (int i = 0; i < 4; i++) {
            int idx4 = tid * 4 + i;
            int r = idx4 >> 4, c4 = (idx4 & 15) * 4;
            float4 f = *(const float4*)(Wi + (size_t)(k0 + r) * 64 + c4);
            T[r][c4 + 0] = f.x; T[r][c4 + 1] = f.y;
            T[r][c4 + 2] = f.z; T[r][c4 + 3] = f.w;
        }
        __syncthreads();
        #pragma unroll
        for (int i = 0; i < 2; i++) {
            int seg = tid * 2 + i;
            int n = seg >> 3, k8 = (seg & 7) * 8;
            bf16x8 v;
            #pragma unroll
            for (int j = 0; j < 8; j++) v[j] = (bf16)T[k8 + j][n];
            *(bf16x8*)(WiT + (size_t)n * 512 + k0 + k8) = v;
        }
    } else {
        const int n0 = (blk - 8) * 64;
        #pragma unroll
        for (int i = 0; i < 4; i++) {
            int idx4 = tid * 4 + i;
            int r = idx4 >> 4, c4 = (idx4 & 15) * 4;
            float4 f = *(const float4*)(Wo + (size_t)r * 512 + n0 + c4);
            T[r][c4 + 0] = f.x; T[r][c4 + 1] = f.y;
            T[r][c4 + 2] = f.z; T[r][c4 + 3] = f.w;
        }
        __syncthreads();
        #pragma unroll
        for (int i = 0; i < 2; i++) {
            int seg = tid * 2 + i;
            int n = seg >> 3, k8 = (seg & 7) * 8;
            bf16x8 v;
            #pragma unroll
            for (int j = 0; j < 8; j++) v[j] = (bf16)T[k8 + j][n];
            *(bf16x8*)(WoT + (size_t)(n0 + n) * 64 + k8) = v;
        }
    }
}

// One block = 16 rows of value. Wave w covers k in [w*128,(w+1)*128). LDS
// reduce -> kvp row-major + kvT[d][s] transposed.
__global__ __launch_bounds__(256, 4) void proj_in_kernel(
    const float* __restrict__ v, const bf16* __restrict__ WiT,
    const float* __restrict__ bi, bf16* __restrict__ kvp,
    bf16* __restrict__ kvT, int K, int S)
{
    __shared__ float P[4][16][68];                    // [wave][row][col]
    const int tid = threadIdx.x;
    const int wave = tid >> 6, lane = tid & 63;
    const int lr = lane & 15, lq = lane >> 4;
    const int row0 = blockIdx.x * 16;
    const float* xrow = v + (size_t)(row0 + lr) * K + wave * 128;
    const bf16* wrow = WiT + wave * 128;

    floatx4 acc[4] = {};
    #pragma unroll
    for (int ks = 0; ks < 4; ks++) {
        const int k0 = ks * 32 + lq * 8;
        float4 a0 = *(const float4*)(xrow + k0);
        float4 a1 = *(const float4*)(xrow + k0 + 4);
        bf16x8 af;
        af[0] = (bf16)a0.x; af[1] = (bf16)a0.y; af[2] = (bf16)a0.z; af[3] = (bf16)a0.w;
        af[4] = (bf16)a1.x; af[5] = (bf16)a1.y; af[6] = (bf16)a1.z; af[7] = (bf16)a1.w;
        #pragma unroll
        for (int t = 0; t < 4; t++) {
            bf16x8 bfv = *(const bf16x8*)(wrow + (size_t)(t * 16 + lr) * K + k0);
            acc[t] = MFMA(af, bfv, acc[t]);
        }
    }
    #pragma unroll
    for (int t = 0; t < 4; t++)
        #pragma unroll
        for (int r = 0; r < 4; r++)
            P[wave][lq * 4 + r][t * 16 + lr] = acc[t][r];
    __syncthreads();

    {   // reduce + row-major write
        const int row = tid >> 4, c4 = (tid & 15) * 4;
        float4 s0 = *(const float4*)&P[0][row][c4];
        float4 s1 = *(const float4*)&P[1][row][c4];
        float4 s2 = *(const float4*)&P[2][row][c4];
        float4 s3 = *(const float4*)&P[3][row][c4];
        float4 bb = *(const float4*)(bi + c4);
        bf16x4 o;
        o[0] = (bf16)(s0.x + s1.x + s2.x + s3.x + bb.x);
        o[1] = (bf16)(s0.y + s1.y + s2.y + s3.y + bb.y);
        o[2] = (bf16)(s0.z + s1.z + s2.z + s3.z + bb.z);
        o[3] = (bf16)(s0.w + s1.w + s2.w + s3.w + bb.w);
        *(bf16x4*)(kvp + (size_t)(row0 + row) * 64 + c4) = o;
    }
    {   // kvT[d][s] transpose write
        const int d = tid >> 2, s4 = (tid & 3) * 4;
        const int b = row0 >> 12, s0r = row0 & (S - 1);
        const float bb = bi[d];
        bf16x4 o;
        #pragma unroll
        for (int i = 0; i < 4; i++) {
            float s = P[0][s4 + i][d] + P[1][s4 + i][d]
                    + P[2][s4 + i][d] + P[3][s4 + i][d] + bb;
            o[i] = (bf16)s;
        }
        *(bf16x4*)(kvT + ((size_t)b * 64 + d) * S + s0r + s4) = o;
    }
}

// One block = one 16-query strip; 4 waves cooperate.
// Phase 0: fused q-proj of own strip (K-split x4, LDS reduce, +bi, *scale).
// Phase 1 (barrier-free per wave): 10 half-chunks (32 keys) split {3,3,2,2}:
//   QK^T -> mask -> private 32-wide S-strip -> PV partial acc.
// Phase 2: reduce acc via LDS -> shared bf16 att strip.
// Phase 3: each wave does 8 of 32 n-tiles of att @ Wo + bo.
__global__ __launch_bounds__(256, 4) void band_attn_out_kernel(
    const float* __restrict__ query, const bf16* __restrict__ WiT,
    const float* __restrict__ bi, const bf16* __restrict__ kvp,
    const bf16* __restrict__ kvT, const int* __restrict__ band_ptr,
    const bf16* __restrict__ WoT, const float* __restrict__ bo,
    float* __restrict__ out, int K, int S, float scale)
{
    __shared__ float P[4][16][68];                    // partials (q-proj, acc)
    __shared__ bf16 Ss[4][16][40];                    // per-wave 32-key S strip
    __shared__ bf16 St[16][88];                       // q strip / att strip
    const int tid = threadIdx.x;
    const int wave = tid >> 6, lane = tid & 63;
    const int lr = lane & 15, lq = lane >> 4;
    const int gs = blockIdx.x;                        // strip id
    const int b = gs >> 8;                            // 256 strips per batch
    const int q0 = (gs & 255) * 16;
    const int band = band_ptr[0];

    // ---- phase 0: q-proj of rows [b*S+q0, +16) ----
    {
        const float* xrow = query + ((size_t)b * S + q0 + lr) * K + wave * 128;
        const bf16* wrow = WiT + wave * 128;
        floatx4 qa[4] = {};
        #pragma unroll
        for (int ks = 0; ks < 4; ks++) {
            const int k0 = ks * 32 + lq * 8;
            float4 a0 = *(const float4*)(xrow + k0);
            float4 a1 = *(const float4*)(xrow + k0 + 4);
            bf16x8 af;
            af[0] = (bf16)a0.x; af[1] = (bf16)a0.y; af[2] = (bf16)a0.z; af[3] = (bf16)a0.w;
            af[4] = (bf16)a1.x; af[5] = (bf16)a1.y; af[6] = (bf16)a1.z; af[7] = (bf16)a1.w;
            #pragma unroll
            for (int t = 0; t < 4; t++) {
                bf16x8 bfv = *(const bf16x8*)(wrow + (size_t)(t * 16 + lr) * K + k0);
                qa[t] = MFMA(af, bfv, qa[t]);
            }
        }
        #pragma unroll
        for (int t = 0; t < 4; t++)
            #pragma unroll
            for (int r = 0; r < 4; r++)
                P[wave][lq * 4 + r][t * 16 + lr] = qa[t][r];
    }
    __syncthreads();
    {   // reduce + bias + scale -> bf16 q strip
        const int row = tid >> 4, c4 = (tid & 15) * 4;
        float4 s0 = *(const float4*)&P[0][row][c4];
        float4 s1 = *(const float4*)&P[1][row][c4];
        float4 s2 = *(const float4*)&P[2][row][c4];
        float4 s3 = *(const float4*)&P[3][row][c4];
        float4 bb = *(const float4*)(bi + c4);
        bf16x4 o;
        o[0] = (bf16)((s0.x + s1.x + s2.x + s3.x + bb.x) * scale);
        o[1] = (bf16)((s0.y + s1.y + s2.y + s3.y + bb.y) * scale);
        o[2] = (bf16)((s0.z + s1.z + s2.z + s3.z + bb.z) * scale);
        o[3] = (bf16)((s0.w + s1.w + s2.w + s3.w + bb.w) * scale);
        *(bf16x4*)(&St[row][c4]) = o;
    }
    __syncthreads();
    bf16x8 qf0 = *(const bf16x8*)(&St[lr][lq * 8]);
    bf16x8 qf1 = *(const bf16x8*)(&St[lr][32 + lq * 8]);

    // ---- phase 1: 10 half-chunks of 32 keys; wave w does {w, w+4, w+8} ----
    floatx4 acc[4] = {};
    const int base = ((q0 - band) >> 6) * 64;         // floor-div chunk base
    #pragma unroll
    for (int i = 0; i < 3; i++) {
        const int h = wave + i * 4;
        if (h < 10) {
            const int kj0 = base + h * 32;
            // QK^T for the 2 key 16-tiles of this half-chunk
            floatx4 sc[2] = {};
            #pragma unroll
            for (int t2 = 0; t2 < 2; t2++) {
                int kr = kj0 + t2 * 16 + lr;
                int krc = min(max(kr, 0), S - 1);     // clamp; masked below
                const bf16* kp = kvp + ((size_t)b * S + krc) * 64;
                bf16x8 b0 = *(const bf16x8*)(kp + lq * 8);
                bf16x8 b1 = *(const bf16x8*)(kp + 32 + lq * 8);
                sc[t2] = MFMA(qf0, b0, sc[t2]);
                sc[t2] = MFMA(qf1, b1, sc[t2]);
            }
            #pragma unroll
            for (int t2 = 0; t2 < 2; t2++) {
                int kj = kj0 + t2 * 16 + lr;
                bool kv_ok = (kj >= 0) && (kj < S);
                #pragma unroll
                for (int r = 0; r < 4; r++) {
                    int qi = q0 + lq * 4 + r;
                    int dlt = qi - kj; dlt = dlt < 0 ? -dlt : dlt;
                    float vv = (kv_ok && dlt <= band) ? sc[t2][r] : 0.f;
                    Ss[wave][lq * 4 + r][t2 * 16 + lr] = (bf16)vv;
                }
            }
            // same-wave LDS write->read: in-order per wave, no barrier needed
            bf16x8 sa = *(const bf16x8*)(&Ss[wave][lr][lq * 8]);
            int kb = kj0 + lq * 8;                    // 8-aligned segment
            int kbc = min(max(kb, 0), S - 8);         // clamp; S entries are 0
            #pragma unroll
            for (int t = 0; t < 4; t++) {
                bf16x8 vb = *(const bf16x8*)(kvT + ((size_t)b * 64 + t * 16 + lr) * S + kbc);
                acc[t] = MFMA(sa, vb, acc[t]);
            }
        }
    }
    #pragma unroll
    for (int t = 0; t < 4; t++)
        #pragma unroll
        for (int r = 0; r < 4; r++)
            P[wave][lq * 4 + r][t * 16 + lr] = acc[t][r];
    __syncthreads();

    // ---- phase 2: reduce 4 partials -> bf16 att strip ----
    {
        const int row = tid >> 4, c4 = (tid & 15) * 4;
        float4 s0 = *(const float4*)&P[0][row][c4];
        float4 s1 = *(const float4*)&P[1][row][c4];
        float4 s2 = *(const float4*)&P[2][row][c4];
        float4 s3 = *(const float4*)&P[3][row][c4];
        bf16x4 o;
        o[0] = (bf16)(s0.x + s1.x + s2.x + s3.x);
        o[1] = (bf16)(s0.y + s1.y + s2.y + s3.y);
        o[2] = (bf16)(s0.z + s1.z + s2.z + s3.z);
        o[3] = (bf16)(s0.w + s1.w + s2.w + s3.w);
        *(bf16x4*)(&St[row][c4]) = o;
    }
    __syncthreads();

    // ---- phase 3: epilogue quarter per wave: n-tiles wave*8 .. wave*8+7 ----
    bf16x8 af0 = *(const bf16x8*)(&St[lr][lq * 8]);
    bf16x8 af1 = *(const bf16x8*)(&St[lr][32 + lq * 8]);
    float* orow = out + ((size_t)b * S + q0) * 512;
    #pragma unroll
    for (int i = 0; i < 8; i++) {
        const int tp = wave * 8 + i;
        const bf16* wp = WoT + (size_t)(tp * 16 + lr) * 64;
        bf16x8 b0 = *(const bf16x8*)(wp + lq * 8);
        bf16x8 b1 = *(const bf16x8*)(wp + 32 + lq * 8);
        floatx4 o = {};
        o = MFMA(af0, b0, o);
        o = MFMA(af1, b1, o);
        float bb = bo[tp * 16 + lr];
        #pragma unroll
        for (int r = 0; r < 4; r++)
            orow[(size_t)(lq * 4 + r) * 512 + tp * 16 + lr] = o[r] + bb;
    }
}

extern "C" void kernel_launch(void* const* d_in, const int* in_sizes, int n_in,
                              void* d_out, int out_size, void* d_ws, size_t ws_size,
                              hipStream_t stream) {
    const float* query = (const float*)d_in[0];
    const float* value = (const float*)d_in[1];
    const float* Wi    = (const float*)d_in[2];
    const float* bi    = (const float*)d_in[3];
    const float* Wo    = (const float*)d_in[4];
    const float* bo    = (const float*)d_in[5];
    const int*   band  = (const int*)d_in[6];
    float* out = (float*)d_out;

    const int Dk = in_sizes[3];            // 64
    const int D  = in_sizes[5];            // 512
    const int S  = 4096;                   // fixed by the benchmark
    const int BS = in_sizes[0] / D;        // 16384
    const int B  = BS / S;                 // 4
    const float scale = 1.0f / sqrtf((float)Dk);

    bf16* WiT = (bf16*)d_ws;
    bf16* WoT = WiT + 32768;
    bf16* kvp = WoT + 32768;
    bf16* kvT = kvp + (size_t)BS * 64;

    prep_weights<<<16, 256, 0, stream>>>(Wi, Wo, WiT, WoT);

    proj_in_kernel<<<dim3(BS / 16), 256, 0, stream>>>(
        value, WiT, bi, kvp, kvT, D, S);

    band_attn_out_kernel<<<dim3(BS / 16), 256, 0, stream>>>(
        query, WiT, bi, kvp, kvT, band, WoT, bo, out, D, S, scale);
}